// Round 2
// baseline (1385.395 us; speedup 1.0000x reference)
//
#include <hip/hip_runtime.h>
#include <math.h>

#define N_NODESC 100000
#define N_EDGESC 1600000
#define NBUCK 1563   // ceil(100000 / 64) -- 64 dst nodes per bucket

// ---------------- degree-out + bucket histogram ----------------
__global__ void deg_kernel(const int* __restrict__ src, const int* __restrict__ dst,
                           int* __restrict__ deg_out, int* __restrict__ bucket_cnt) {
    int i = blockIdx.x * blockDim.x + threadIdx.x;
    if (i < N_EDGESC) {
        atomicAdd(&deg_out[src[i]], 1);
        atomicAdd(&bucket_cnt[dst[i] >> 6], 1);
    }
}

// ---------------- fused fc1 (tanh) + filt GEMM, xs = x * inv_sqrt_out ----------------
__global__ __launch_bounds__(256) void gemm_kernel(
    const float* __restrict__ feat,
    const float* __restrict__ w1, const float* __restrict__ b1,
    const float* __restrict__ w2, const float* __restrict__ b2,
    const int* __restrict__ deg_out,
    float* __restrict__ h1, float* __restrict__ xs) {
    __shared__ float sf[128 * 68];
    int tid = threadIdx.x;
    int base = blockIdx.x * 128;
    for (int k = 0; k < 8; k++) {
        int fi = tid + k * 256;
        int node = fi >> 4, f4 = fi & 15;
        float4 v = make_float4(0.f, 0.f, 0.f, 0.f);
        if (base + node < N_NODESC)
            v = ((const float4*)feat)[(size_t)(base + node) * 16 + f4];
        float* d = &sf[node * 68 + f4 * 4];
        d[0] = v.x; d[1] = v.y; d[2] = v.z; d[3] = v.w;
    }
    __syncthreads();

    int lane = tid & 63;
    int og = __builtin_amdgcn_readfirstlane(tid >> 6);
    const float* wp1 = w1 + og * 16 * 64;
    const float* wp2 = w2 + og * 16 * 64;

    float a1[2][16], a2[2][16];
#pragma unroll
    for (int o = 0; o < 16; o++) {
        float bb1 = b1[og * 16 + o], bb2 = b2[og * 16 + o];
        a1[0][o] = bb1; a1[1][o] = bb1;
        a2[0][o] = bb2; a2[1][o] = bb2;
    }

    for (int fq = 0; fq < 16; fq++) {
        float4 fv0 = *(const float4*)&sf[lane * 68 + fq * 4];
        float4 fv1 = *(const float4*)&sf[(lane + 64) * 68 + fq * 4];
#pragma unroll
        for (int o = 0; o < 16; o++) {
            float4 wv1 = *(const float4*)&wp1[o * 64 + fq * 4];
            float4 wv2 = *(const float4*)&wp2[o * 64 + fq * 4];
            a1[0][o] += fv0.x * wv1.x + fv0.y * wv1.y + fv0.z * wv1.z + fv0.w * wv1.w;
            a1[1][o] += fv1.x * wv1.x + fv1.y * wv1.y + fv1.z * wv1.z + fv1.w * wv1.w;
            a2[0][o] += fv0.x * wv2.x + fv0.y * wv2.y + fv0.z * wv2.z + fv0.w * wv2.w;
            a2[1][o] += fv1.x * wv2.x + fv1.y * wv2.y + fv1.z * wv2.z + fv1.w * wv2.w;
        }
    }

#pragma unroll
    for (int j = 0; j < 2; j++) {
        int g = base + lane + j * 64;
        if (g >= N_NODESC) continue;
        float is = rsqrtf(fmaxf((float)deg_out[g], 1.f));
#pragma unroll
        for (int oq = 0; oq < 4; oq++) {
            float4 t, u;
            t.x = tanhf(a1[j][oq * 4 + 0]); t.y = tanhf(a1[j][oq * 4 + 1]);
            t.z = tanhf(a1[j][oq * 4 + 2]); t.w = tanhf(a1[j][oq * 4 + 3]);
            u.x = a2[j][oq * 4 + 0] * is;   u.y = a2[j][oq * 4 + 1] * is;
            u.z = a2[j][oq * 4 + 2] * is;   u.w = a2[j][oq * 4 + 3] * is;
            ((float4*)h1)[(size_t)g * 16 + og * 4 + oq] = t;
            ((float4*)xs)[(size_t)g * 16 + og * 4 + oq] = u;
        }
    }
}

// ---------------- single-block exclusive scan of bucket counts ----------------
__global__ __launch_bounds__(1024) void bscan_kernel(const int* __restrict__ cnt,
                                                     int* __restrict__ boff,
                                                     int* __restrict__ bcur) {
    int t = threadIdx.x;
    int c0 = (2 * t < NBUCK) ? cnt[2 * t] : 0;
    int c1 = (2 * t + 1 < NBUCK) ? cnt[2 * t + 1] : 0;
    int pair = c0 + c1;
    int lane = t & 63, wid = t >> 6;
    int v = pair;
#pragma unroll
    for (int off = 1; off < 64; off <<= 1) {
        int tv = __shfl_up(v, off, 64);
        if (lane >= off) v += tv;
    }
    __shared__ int ws[16];
    if (lane == 63) ws[wid] = v;
    __syncthreads();
    if (wid == 0) {
        int s = (lane < 16) ? ws[lane] : 0;
#pragma unroll
        for (int off = 1; off < 16; off <<= 1) {
            int tv = __shfl_up(s, off, 64);
            if (lane >= off) s += tv;
        }
        if (lane < 16) ws[lane] = s;
    }
    __syncthreads();
    int incl = v + ((wid > 0) ? ws[wid - 1] : 0);
    int excl = incl - pair;
    if (2 * t < NBUCK)     { boff[2 * t] = excl;          bcur[2 * t] = excl; }
    if (2 * t + 1 < NBUCK) { boff[2 * t + 1] = excl + c0; bcur[2 * t + 1] = excl + c0; }
    if (t == 1023) boff[NBUCK] = incl;   // == N_EDGESC
}

// ---------------- pass 1: scatter packed edges into bucket regions ----------------
// Writes within a bucket hit consecutive slots -> 64B lines fill completely
// before writeback (write traffic ~6.4 MB instead of 64B/edge = 102 MB).
__global__ void scatter_kernel(const int* __restrict__ src, const int* __restrict__ dst,
                               int* __restrict__ bcur, unsigned* __restrict__ bedges) {
    int i = blockIdx.x * blockDim.x + threadIdx.x;
    if (i < N_EDGESC) {
        int s = src[i], d = dst[i];
        int slot = atomicAdd(&bcur[d >> 6], 1);
        bedges[slot] = (unsigned)s | ((unsigned)(d & 63) << 17);
    }
}

// ---------------- pass 2: fused per-bucket aggregation ----------------
// One block per bucket (64 dst nodes). Stream the bucket's edges, gather
// xs[src] rows (coalesced 256B, L2/L3-resident), accumulate into a 64x64
// LDS accumulator via ds_add_f32 (lane=feature: conflict-free), count
// deg_in locally, normalize, write h2 coalesced.
__global__ __launch_bounds__(256) void agg2_kernel(const int* __restrict__ boff,
                                                   const unsigned* __restrict__ bedges,
                                                   const float* __restrict__ xs,
                                                   float* __restrict__ h2) {
    __shared__ float lacc[64 * 64];   // 16 KB
    __shared__ int lcnt[64];
    int tid = threadIdx.x;
    int lane = tid & 63, wid = tid >> 6;
    for (int k = tid; k < 64 * 64; k += 256) lacc[k] = 0.f;
    if (tid < 64) lcnt[tid] = 0;
    __syncthreads();

    int b = blockIdx.x;
    int beg = boff[b], end = boff[b + 1];
    for (int e = beg + wid; e < end; e += 4) {
        unsigned pk = bedges[e];
        int s  = (int)(pk & 0x1FFFFu);
        int dl = (int)(pk >> 17) & 63;
        float v = xs[(size_t)s * 64 + lane];
        atomicAdd(&lacc[dl * 64 + lane], v);
        if (lane == 0) atomicAdd(&lcnt[dl], 1);
    }
    __syncthreads();

    int nbase = b * 64;
    for (int n = wid; n < 64; n += 4) {
        int g = nbase + n;
        if (g >= N_NODESC) continue;
        float isq = rsqrtf(fmaxf((float)lcnt[n], 1.f));
        h2[(size_t)g * 64 + lane] = lacc[n * 64 + lane] * isq;
    }
}

// ---------------- channel-attention scores (sum over nodes) ----------------
__global__ __launch_bounds__(256) void att_kernel(const float* __restrict__ h1,
                                                  const float* __restrict__ h2,
                                                  const float* __restrict__ aw1,
                                                  const float* __restrict__ ab1,
                                                  const float* __restrict__ aw2,
                                                  float* __restrict__ wsum) {
    int n = blockIdx.x * 256 + threadIdx.x;
    float sc[2] = {0.f, 0.f};
    if (n < N_NODESC) {
#pragma unroll
        for (int c = 0; c < 2; c++) {
            const float* row = (c == 0 ? h1 : h2) + (size_t)n * 64;
            float acc[32];
#pragma unroll
            for (int k = 0; k < 32; k++) acc[k] = ab1[k];
            for (int fq = 0; fq < 16; fq++) {
                float4 rv = ((const float4*)row)[fq];
#pragma unroll
                for (int k = 0; k < 32; k++) {
                    acc[k] += rv.x * aw1[(fq * 4 + 0) * 32 + k]
                            + rv.y * aw1[(fq * 4 + 1) * 32 + k]
                            + rv.z * aw1[(fq * 4 + 2) * 32 + k]
                            + rv.w * aw1[(fq * 4 + 3) * 32 + k];
                }
            }
            float s = 0.f;
#pragma unroll
            for (int k = 0; k < 32; k++) s += tanhf(acc[k]) * aw2[k];
            sc[c] = s;
        }
    }
#pragma unroll
    for (int off = 32; off; off >>= 1) {
        sc[0] += __shfl_down(sc[0], off, 64);
        sc[1] += __shfl_down(sc[1], off, 64);
    }
    if ((threadIdx.x & 63) == 0) {
        atomicAdd(&wsum[0], sc[0]);
        atomicAdd(&wsum[1], sc[1]);
    }
}

__global__ void beta_kernel(const float* __restrict__ wsum, float* __restrict__ beta) {
    float w0 = wsum[0] / (float)N_NODESC, w1 = wsum[1] / (float)N_NODESC;
    float m = fmaxf(w0, w1);
    float e0 = expf(w0 - m), e1 = expf(w1 - m);
    float inv = 1.f / (e0 + e1);
    beta[0] = e0 * inv;
    beta[1] = e1 * inv;
}

// ---------------- fused combine + fc2 ----------------
__global__ __launch_bounds__(256) void out_kernel(const float* __restrict__ h1,
                                                  const float* __restrict__ h2,
                                                  const float* __restrict__ beta,
                                                  const float* __restrict__ w,
                                                  const float* __restrict__ b,
                                                  float* __restrict__ out) {
    __shared__ float sw[16 * 68];
    int tid = threadIdx.x;
    {
        int o = tid >> 4, f4 = tid & 15;
        float4 v = ((const float4*)w)[tid];
        float* d = &sw[o * 68 + f4 * 4];
        d[0] = v.x; d[1] = v.y; d[2] = v.z; d[3] = v.w;
    }
    __syncthreads();
    int o = tid & 15, ln = tid >> 4;
    int node = blockIdx.x * 16 + ln;
    if (node >= N_NODESC) return;
    float b0 = beta[0], b1v = beta[1];
    const float4* r1 = (const float4*)(h1 + (size_t)node * 64);
    const float4* r2 = (const float4*)(h2 + (size_t)node * 64);
    float acc = b[o];
    for (int fq = 0; fq < 16; fq++) {
        float4 x1 = r1[fq], x2 = r2[fq];
        float4 wv = *(const float4*)&sw[o * 68 + fq * 4];
        acc += (b0 * x1.x + b1v * x2.x) * wv.x + (b0 * x1.y + b1v * x2.y) * wv.y
             + (b0 * x1.z + b1v * x2.z) * wv.z + (b0 * x1.w + b1v * x2.w) * wv.w;
    }
    out[(size_t)node * 16 + o] = acc;
}

extern "C" void kernel_launch(void* const* d_in, const int* in_sizes, int n_in,
                              void* d_out, int out_size, void* d_ws, size_t ws_size,
                              hipStream_t stream) {
    (void)in_sizes; (void)n_in; (void)out_size; (void)ws_size;
    const float* feat = (const float*)d_in[0];
    const int*   esrc = (const int*)d_in[1];
    const int*   edst = (const int*)d_in[2];
    const float* fc1w = (const float*)d_in[3];
    const float* fc1b = (const float*)d_in[4];
    const float* fltw = (const float*)d_in[5];
    const float* fltb = (const float*)d_in[6];
    const float* aw1  = (const float*)d_in[7];
    const float* ab1  = (const float*)d_in[8];
    const float* aw2  = (const float*)d_in[9];
    const float* fc2w = (const float*)d_in[10];
    const float* fc2b = (const float*)d_in[11];
    float* out = (float*)d_out;

    char* ws = (char*)d_ws;
    size_t off = 0;
    auto alloc = [&](size_t bytes) {
        char* p = ws + off;
        off += (bytes + 255) & ~(size_t)255;
        return p;
    };
    float*    h1       = (float*)alloc((size_t)N_NODESC * 64 * 4);
    float*    xs       = (float*)alloc((size_t)N_NODESC * 64 * 4);
    float*    h2       = (float*)alloc((size_t)N_NODESC * 64 * 4);
    int*      deg_out  = (int*)alloc((size_t)N_NODESC * 4);
    int*      bcnt     = (int*)alloc((size_t)NBUCK * 4);
    int*      boff     = (int*)alloc((size_t)(NBUCK + 1) * 4);
    int*      bcur     = (int*)alloc((size_t)NBUCK * 4);
    unsigned* bedges   = (unsigned*)alloc((size_t)N_EDGESC * 4);
    float*    wsum     = (float*)alloc(16 * 4);
    float*    beta     = (float*)alloc(16 * 4);

    hipMemsetAsync(deg_out, 0, (size_t)N_NODESC * 4, stream);
    hipMemsetAsync(bcnt, 0, (size_t)NBUCK * 4, stream);
    hipMemsetAsync(wsum, 0, 2 * 4, stream);

    deg_kernel<<<(N_EDGESC + 255) / 256, 256, 0, stream>>>(esrc, edst, deg_out, bcnt);
    gemm_kernel<<<(N_NODESC + 127) / 128, 256, 0, stream>>>(
        feat, fc1w, fc1b, fltw, fltb, deg_out, h1, xs);
    bscan_kernel<<<1, 1024, 0, stream>>>(bcnt, boff, bcur);
    scatter_kernel<<<(N_EDGESC + 255) / 256, 256, 0, stream>>>(esrc, edst, bcur, bedges);
    agg2_kernel<<<NBUCK, 256, 0, stream>>>(boff, bedges, xs, h2);
    att_kernel<<<(N_NODESC + 255) / 256, 256, 0, stream>>>(h1, h2, aw1, ab1, aw2, wsum);
    beta_kernel<<<1, 1, 0, stream>>>(wsum, beta);
    out_kernel<<<(N_NODESC + 15) / 16, 256, 0, stream>>>(h1, h2, beta, fc2w, fc2b, out);
}

// Round 3
// 992.206 us; speedup vs baseline: 1.3963x; 1.3963x over previous
//
#include <hip/hip_runtime.h>
#include <math.h>

#define N_NODESC 100000
#define N_EDGESC 1600000
#define NBUCK 1563        // ceil(100000 / 64) -- 64 dst nodes per bucket
#define BSLACK 1280       // slots per bucket region (mean 1024 + 8 sigma)
#define SCHUNK 16384      // edges per scatter block
#define NSBLK 98          // ceil(1.6M / 16384)

// ---------------- degree histograms ----------------
__global__ void deg_kernel(const int* __restrict__ src, const int* __restrict__ dst,
                           int* __restrict__ deg_out, int* __restrict__ deg_in) {
    int i = blockIdx.x * blockDim.x + threadIdx.x;
    if (i < N_EDGESC) {
        atomicAdd(&deg_out[src[i]], 1);
        atomicAdd(&deg_in[dst[i]], 1);
    }
}

__global__ void binit_kernel(int* __restrict__ bcur) {
    int i = blockIdx.x * blockDim.x + threadIdx.x;
    if (i < NBUCK) bcur[i] = i * BSLACK;
}

// ---------------- fused fc1 (tanh) + filt GEMM, xs = x * inv_sqrt_out ----------------
__global__ __launch_bounds__(256) void gemm_kernel(
    const float* __restrict__ feat,
    const float* __restrict__ w1, const float* __restrict__ b1,
    const float* __restrict__ w2, const float* __restrict__ b2,
    const int* __restrict__ deg_out,
    float* __restrict__ h1, float* __restrict__ xs) {
    __shared__ float sf[128 * 68];
    int tid = threadIdx.x;
    int base = blockIdx.x * 128;
    for (int k = 0; k < 8; k++) {
        int fi = tid + k * 256;
        int node = fi >> 4, f4 = fi & 15;
        float4 v = make_float4(0.f, 0.f, 0.f, 0.f);
        if (base + node < N_NODESC)
            v = ((const float4*)feat)[(size_t)(base + node) * 16 + f4];
        float* d = &sf[node * 68 + f4 * 4];
        d[0] = v.x; d[1] = v.y; d[2] = v.z; d[3] = v.w;
    }
    __syncthreads();

    int lane = tid & 63;
    int og = __builtin_amdgcn_readfirstlane(tid >> 6);
    const float* wp1 = w1 + og * 16 * 64;
    const float* wp2 = w2 + og * 16 * 64;

    float a1[2][16], a2[2][16];
#pragma unroll
    for (int o = 0; o < 16; o++) {
        float bb1 = b1[og * 16 + o], bb2 = b2[og * 16 + o];
        a1[0][o] = bb1; a1[1][o] = bb1;
        a2[0][o] = bb2; a2[1][o] = bb2;
    }

    for (int fq = 0; fq < 16; fq++) {
        float4 fv0 = *(const float4*)&sf[lane * 68 + fq * 4];
        float4 fv1 = *(const float4*)&sf[(lane + 64) * 68 + fq * 4];
#pragma unroll
        for (int o = 0; o < 16; o++) {
            float4 wv1 = *(const float4*)&wp1[o * 64 + fq * 4];
            float4 wv2 = *(const float4*)&wp2[o * 64 + fq * 4];
            a1[0][o] += fv0.x * wv1.x + fv0.y * wv1.y + fv0.z * wv1.z + fv0.w * wv1.w;
            a1[1][o] += fv1.x * wv1.x + fv1.y * wv1.y + fv1.z * wv1.z + fv1.w * wv1.w;
            a2[0][o] += fv0.x * wv2.x + fv0.y * wv2.y + fv0.z * wv2.z + fv0.w * wv2.w;
            a2[1][o] += fv1.x * wv2.x + fv1.y * wv2.y + fv1.z * wv2.z + fv1.w * wv2.w;
        }
    }

#pragma unroll
    for (int j = 0; j < 2; j++) {
        int g = base + lane + j * 64;
        if (g >= N_NODESC) continue;
        float is = rsqrtf(fmaxf((float)deg_out[g], 1.f));
#pragma unroll
        for (int oq = 0; oq < 4; oq++) {
            float4 t, u;
            t.x = tanhf(a1[j][oq * 4 + 0]); t.y = tanhf(a1[j][oq * 4 + 1]);
            t.z = tanhf(a1[j][oq * 4 + 2]); t.w = tanhf(a1[j][oq * 4 + 3]);
            u.x = a2[j][oq * 4 + 0] * is;   u.y = a2[j][oq * 4 + 1] * is;
            u.z = a2[j][oq * 4 + 2] * is;   u.w = a2[j][oq * 4 + 3] * is;
            ((float4*)h1)[(size_t)g * 16 + og * 4 + oq] = t;
            ((float4*)xs)[(size_t)g * 16 + og * 4 + oq] = u;
        }
    }
}

// ---------------- per-block staged counting sort into fixed bucket regions ----------------
// LDS histogram -> one global atomic per (block,bucket) to reserve a contiguous
// run -> place via LDS cursors. Cuts global-cursor contention 1024 -> 98 per
// address and makes slot writes ~42B contiguous runs per block.
__global__ __launch_bounds__(1024) void scatter2_kernel(const int* __restrict__ src,
                                                        const int* __restrict__ dst,
                                                        int* __restrict__ bcur,
                                                        unsigned* __restrict__ bedges) {
    __shared__ int hist[NBUCK];
    int tid = threadIdx.x;
    int e_beg = blockIdx.x * SCHUNK;
    int e_end = min(e_beg + SCHUNK, N_EDGESC);
    for (int i = tid; i < NBUCK; i += 1024) hist[i] = 0;
    __syncthreads();
#pragma unroll 4
    for (int i = e_beg + tid; i < e_end; i += 1024)
        atomicAdd(&hist[dst[i] >> 6], 1);
    __syncthreads();
    for (int i = tid; i < NBUCK; i += 1024) {
        int c = hist[i];
        if (c > 0) hist[i] = atomicAdd(&bcur[i], c);
    }
    __syncthreads();
#pragma unroll 4
    for (int i = e_beg + tid; i < e_end; i += 1024) {
        int s = src[i], d = dst[i];
        int slot = atomicAdd(&hist[d >> 6], 1);
        bedges[slot] = (unsigned)s | ((unsigned)(d & 63) << 17);
    }
}

// ---------------- fused per-bucket aggregation, 32 gathers in flight per wave ----------------
__global__ __launch_bounds__(256) void agg3_kernel(const int* __restrict__ bcur,
                                                   const unsigned* __restrict__ bedges,
                                                   const float* __restrict__ xs,
                                                   const int* __restrict__ deg_in,
                                                   float* __restrict__ h2) {
    __shared__ float lacc[64 * 64];   // 16 KB
    int tid = threadIdx.x;
    int lane = tid & 63, wid = tid >> 6;
    for (int k = tid; k < 64 * 64; k += 256) lacc[k] = 0.f;
    __syncthreads();

    int b = blockIdx.x;
    int beg = b * BSLACK;
    int end = bcur[b];                // final cursor == beg + bucket count

    for (int e0 = beg + wid * 32; e0 < end; e0 += 128) {
        int n = end - e0; if (n > 32) n = 32;
        unsigned pk = bedges[min(e0 + (lane & 31), end - 1)];
        float v[32]; int dl[32];
#pragma unroll
        for (int j = 0; j < 32; j++) {
            unsigned p = (unsigned)__builtin_amdgcn_readlane((int)pk, j);
            dl[j] = (int)(p >> 17);
            v[j] = xs[(size_t)(p & 0x1FFFFu) * 64 + lane];
        }
#pragma unroll
        for (int j = 0; j < 32; j++) {
            float vv = (j < n) ? v[j] : 0.f;   // padded lanes add 0
            atomicAdd(&lacc[dl[j] * 64 + lane], vv);
        }
    }
    __syncthreads();

    int nbase = b * 64;
    for (int nl = wid; nl < 64; nl += 4) {
        int g = nbase + nl;
        if (g >= N_NODESC) continue;
        float isq = rsqrtf(fmaxf((float)deg_in[g], 1.f));
        h2[(size_t)g * 64 + lane] = lacc[nl * 64 + lane] * isq;
    }
}

// ---------------- channel-attention scores (sum over nodes) ----------------
__global__ __launch_bounds__(256) void att_kernel(const float* __restrict__ h1,
                                                  const float* __restrict__ h2,
                                                  const float* __restrict__ aw1,
                                                  const float* __restrict__ ab1,
                                                  const float* __restrict__ aw2,
                                                  float* __restrict__ wsum) {
    int n = blockIdx.x * 256 + threadIdx.x;
    float sc[2] = {0.f, 0.f};
    if (n < N_NODESC) {
#pragma unroll
        for (int c = 0; c < 2; c++) {
            const float* row = (c == 0 ? h1 : h2) + (size_t)n * 64;
            float acc[32];
#pragma unroll
            for (int k = 0; k < 32; k++) acc[k] = ab1[k];
            for (int fq = 0; fq < 16; fq++) {
                float4 rv = ((const float4*)row)[fq];
#pragma unroll
                for (int k = 0; k < 32; k++) {
                    acc[k] += rv.x * aw1[(fq * 4 + 0) * 32 + k]
                            + rv.y * aw1[(fq * 4 + 1) * 32 + k]
                            + rv.z * aw1[(fq * 4 + 2) * 32 + k]
                            + rv.w * aw1[(fq * 4 + 3) * 32 + k];
                }
            }
            float s = 0.f;
#pragma unroll
            for (int k = 0; k < 32; k++) s += tanhf(acc[k]) * aw2[k];
            sc[c] = s;
        }
    }
#pragma unroll
    for (int off = 32; off; off >>= 1) {
        sc[0] += __shfl_down(sc[0], off, 64);
        sc[1] += __shfl_down(sc[1], off, 64);
    }
    if ((threadIdx.x & 63) == 0) {
        atomicAdd(&wsum[0], sc[0]);
        atomicAdd(&wsum[1], sc[1]);
    }
}

__global__ void beta_kernel(const float* __restrict__ wsum, float* __restrict__ beta) {
    float w0 = wsum[0] / (float)N_NODESC, w1 = wsum[1] / (float)N_NODESC;
    float m = fmaxf(w0, w1);
    float e0 = expf(w0 - m), e1 = expf(w1 - m);
    float inv = 1.f / (e0 + e1);
    beta[0] = e0 * inv;
    beta[1] = e1 * inv;
}

// ---------------- fused combine + fc2 ----------------
__global__ __launch_bounds__(256) void out_kernel(const float* __restrict__ h1,
                                                  const float* __restrict__ h2,
                                                  const float* __restrict__ beta,
                                                  const float* __restrict__ w,
                                                  const float* __restrict__ b,
                                                  float* __restrict__ out) {
    __shared__ float sw[16 * 68];
    int tid = threadIdx.x;
    {
        int o = tid >> 4, f4 = tid & 15;
        float4 v = ((const float4*)w)[tid];
        float* d = &sw[o * 68 + f4 * 4];
        d[0] = v.x; d[1] = v.y; d[2] = v.z; d[3] = v.w;
    }
    __syncthreads();
    int o = tid & 15, ln = tid >> 4;
    int node = blockIdx.x * 16 + ln;
    if (node >= N_NODESC) return;
    float b0 = beta[0], b1v = beta[1];
    const float4* r1 = (const float4*)(h1 + (size_t)node * 64);
    const float4* r2 = (const float4*)(h2 + (size_t)node * 64);
    float acc = b[o];
    for (int fq = 0; fq < 16; fq++) {
        float4 x1 = r1[fq], x2 = r2[fq];
        float4 wv = *(const float4*)&sw[o * 68 + fq * 4];
        acc += (b0 * x1.x + b1v * x2.x) * wv.x + (b0 * x1.y + b1v * x2.y) * wv.y
             + (b0 * x1.z + b1v * x2.z) * wv.z + (b0 * x1.w + b1v * x2.w) * wv.w;
    }
    out[(size_t)node * 16 + o] = acc;
}

extern "C" void kernel_launch(void* const* d_in, const int* in_sizes, int n_in,
                              void* d_out, int out_size, void* d_ws, size_t ws_size,
                              hipStream_t stream) {
    (void)in_sizes; (void)n_in; (void)out_size; (void)ws_size;
    const float* feat = (const float*)d_in[0];
    const int*   esrc = (const int*)d_in[1];
    const int*   edst = (const int*)d_in[2];
    const float* fc1w = (const float*)d_in[3];
    const float* fc1b = (const float*)d_in[4];
    const float* fltw = (const float*)d_in[5];
    const float* fltb = (const float*)d_in[6];
    const float* aw1  = (const float*)d_in[7];
    const float* ab1  = (const float*)d_in[8];
    const float* aw2  = (const float*)d_in[9];
    const float* fc2w = (const float*)d_in[10];
    const float* fc2b = (const float*)d_in[11];
    float* out = (float*)d_out;

    char* ws = (char*)d_ws;
    size_t off = 0;
    auto alloc = [&](size_t bytes) {
        char* p = ws + off;
        off += (bytes + 255) & ~(size_t)255;
        return p;
    };
    float*    h1      = (float*)alloc((size_t)N_NODESC * 64 * 4);
    float*    xs      = (float*)alloc((size_t)N_NODESC * 64 * 4);
    float*    h2      = (float*)alloc((size_t)N_NODESC * 64 * 4);
    int*      deg_out = (int*)alloc((size_t)N_NODESC * 4);
    int*      deg_in  = (int*)alloc((size_t)N_NODESC * 4);
    int*      bcur    = (int*)alloc((size_t)NBUCK * 4);
    unsigned* bedges  = (unsigned*)alloc((size_t)NBUCK * BSLACK * 4);  // 8 MB
    float*    wsum    = (float*)alloc(16 * 4);
    float*    beta    = (float*)alloc(16 * 4);

    hipMemsetAsync(deg_out, 0, (size_t)N_NODESC * 4, stream);
    hipMemsetAsync(deg_in, 0, (size_t)N_NODESC * 4, stream);
    hipMemsetAsync(wsum, 0, 2 * 4, stream);

    binit_kernel<<<(NBUCK + 255) / 256, 256, 0, stream>>>(bcur);
    deg_kernel<<<(N_EDGESC + 255) / 256, 256, 0, stream>>>(esrc, edst, deg_out, deg_in);
    scatter2_kernel<<<NSBLK, 1024, 0, stream>>>(esrc, edst, bcur, bedges);
    gemm_kernel<<<(N_NODESC + 127) / 128, 256, 0, stream>>>(
        feat, fc1w, fc1b, fltw, fltb, deg_out, h1, xs);
    agg3_kernel<<<NBUCK, 256, 0, stream>>>(bcur, bedges, xs, deg_in, h2);
    att_kernel<<<(N_NODESC + 255) / 256, 256, 0, stream>>>(h1, h2, aw1, ab1, aw2, wsum);
    beta_kernel<<<1, 1, 0, stream>>>(wsum, beta);
    out_kernel<<<(N_NODESC + 15) / 16, 256, 0, stream>>>(h1, h2, beta, fc2w, fc2b, out);
}

// Round 4
// 385.872 us; speedup vs baseline: 3.5903x; 2.5713x over previous
//
#include <hip/hip_runtime.h>
#include <math.h>

#define N_NODESC 100000
#define N_EDGESC 1600000
#define NBUCK 1563        // ceil(100000 / 64) -- 64 dst nodes per bucket
#define BSLACK 1280       // slots per bucket region (mean 1024 + 8 sigma)
#define SCHUNK 16384      // edges per scatter block
#define NSBLK 98          // ceil(1.6M / 16384)

// ---------------- out-degree histogram (deg_in now computed inside agg4) ----------------
__global__ void deg_kernel(const int* __restrict__ src, int* __restrict__ deg_out) {
    int i = blockIdx.x * blockDim.x + threadIdx.x;
    if (i < N_EDGESC) atomicAdd(&deg_out[src[i]], 1);
}

__global__ void binit_kernel(int* __restrict__ bcur) {
    int i = blockIdx.x * blockDim.x + threadIdx.x;
    if (i < NBUCK) bcur[i] = i * BSLACK;
}

// ---------------- fused fc1 (tanh) + filt GEMM, xs = x * inv_sqrt_out ----------------
__global__ __launch_bounds__(256) void gemm_kernel(
    const float* __restrict__ feat,
    const float* __restrict__ w1, const float* __restrict__ b1,
    const float* __restrict__ w2, const float* __restrict__ b2,
    const int* __restrict__ deg_out,
    float* __restrict__ h1, float* __restrict__ xs) {
    __shared__ float sf[128 * 68];
    int tid = threadIdx.x;
    int base = blockIdx.x * 128;
    for (int k = 0; k < 8; k++) {
        int fi = tid + k * 256;
        int node = fi >> 4, f4 = fi & 15;
        float4 v = make_float4(0.f, 0.f, 0.f, 0.f);
        if (base + node < N_NODESC)
            v = ((const float4*)feat)[(size_t)(base + node) * 16 + f4];
        float* d = &sf[node * 68 + f4 * 4];
        d[0] = v.x; d[1] = v.y; d[2] = v.z; d[3] = v.w;
    }
    __syncthreads();

    int lane = tid & 63;
    int og = __builtin_amdgcn_readfirstlane(tid >> 6);
    const float* wp1 = w1 + og * 16 * 64;
    const float* wp2 = w2 + og * 16 * 64;

    float a1[2][16], a2[2][16];
#pragma unroll
    for (int o = 0; o < 16; o++) {
        float bb1 = b1[og * 16 + o], bb2 = b2[og * 16 + o];
        a1[0][o] = bb1; a1[1][o] = bb1;
        a2[0][o] = bb2; a2[1][o] = bb2;
    }

    for (int fq = 0; fq < 16; fq++) {
        float4 fv0 = *(const float4*)&sf[lane * 68 + fq * 4];
        float4 fv1 = *(const float4*)&sf[(lane + 64) * 68 + fq * 4];
#pragma unroll
        for (int o = 0; o < 16; o++) {
            float4 wv1 = *(const float4*)&wp1[o * 64 + fq * 4];
            float4 wv2 = *(const float4*)&wp2[o * 64 + fq * 4];
            a1[0][o] += fv0.x * wv1.x + fv0.y * wv1.y + fv0.z * wv1.z + fv0.w * wv1.w;
            a1[1][o] += fv1.x * wv1.x + fv1.y * wv1.y + fv1.z * wv1.z + fv1.w * wv1.w;
            a2[0][o] += fv0.x * wv2.x + fv0.y * wv2.y + fv0.z * wv2.z + fv0.w * wv2.w;
            a2[1][o] += fv1.x * wv2.x + fv1.y * wv2.y + fv1.z * wv2.z + fv1.w * wv2.w;
        }
    }

#pragma unroll
    for (int j = 0; j < 2; j++) {
        int g = base + lane + j * 64;
        if (g >= N_NODESC) continue;
        float is = rsqrtf(fmaxf((float)deg_out[g], 1.f));
#pragma unroll
        for (int oq = 0; oq < 4; oq++) {
            float4 t, u;
            t.x = tanhf(a1[j][oq * 4 + 0]); t.y = tanhf(a1[j][oq * 4 + 1]);
            t.z = tanhf(a1[j][oq * 4 + 2]); t.w = tanhf(a1[j][oq * 4 + 3]);
            u.x = a2[j][oq * 4 + 0] * is;   u.y = a2[j][oq * 4 + 1] * is;
            u.z = a2[j][oq * 4 + 2] * is;   u.w = a2[j][oq * 4 + 3] * is;
            ((float4*)h1)[(size_t)g * 16 + og * 4 + oq] = t;
            ((float4*)xs)[(size_t)g * 16 + og * 4 + oq] = u;
        }
    }
}

// ---------------- per-block staged counting sort into fixed bucket regions ----------------
__global__ __launch_bounds__(1024) void scatter2_kernel(const int* __restrict__ src,
                                                        const int* __restrict__ dst,
                                                        int* __restrict__ bcur,
                                                        unsigned* __restrict__ bedges) {
    __shared__ int hist[NBUCK];
    int tid = threadIdx.x;
    int e_beg = blockIdx.x * SCHUNK;
    int e_end = min(e_beg + SCHUNK, N_EDGESC);
    for (int i = tid; i < NBUCK; i += 1024) hist[i] = 0;
    __syncthreads();
#pragma unroll 4
    for (int i = e_beg + tid; i < e_end; i += 1024)
        atomicAdd(&hist[dst[i] >> 6], 1);
    __syncthreads();
    for (int i = tid; i < NBUCK; i += 1024) {
        int c = hist[i];
        if (c > 0) hist[i] = atomicAdd(&bcur[i], c);
    }
    __syncthreads();
#pragma unroll 4
    for (int i = e_beg + tid; i < e_end; i += 1024) {
        int s = src[i], d = dst[i];
        int slot = atomicAdd(&hist[d >> 6], 1);
        bedges[slot] = (unsigned)s | ((unsigned)(d & 63) << 17);
    }
}

// ---------------- per-bucket: LDS node-sort, then wave-per-node register accumulation ----------------
// Stage bucket edges in LDS + histogram 64 local dsts (== deg_in), 64-wide scan,
// LDS counting sort to node order. Then each wave owns 16 nodes; per node:
// read <=16 srcs from LDS, shfl-broadcast, issue up to 16 independent 256B
// coalesced gathers into registers, fold into a per-node register accumulator.
__global__ __launch_bounds__(256) void agg4_kernel(const int* __restrict__ bcur,
                                                   const unsigned* __restrict__ bedges,
                                                   const float* __restrict__ xs,
                                                   float* __restrict__ h2) {
    __shared__ unsigned eraw[BSLACK];
    __shared__ unsigned eled[BSLACK];
    __shared__ int loff[65];
    __shared__ int lcnt[64];
    __shared__ int lcur[64];
    int tid = threadIdx.x, lane = tid & 63, wid = tid >> 6;
    int b = blockIdx.x;
    int beg = b * BSLACK;
    int m = bcur[b] - beg;             // edges in this bucket

    if (tid < 64) lcnt[tid] = 0;
    __syncthreads();
    for (int i = tid; i < m; i += 256) {
        unsigned pk = bedges[beg + i];
        eraw[i] = pk;
        atomicAdd(&lcnt[pk >> 17], 1);
    }
    __syncthreads();
    if (wid == 0) {                    // 64-entry exclusive scan in wave 0
        int c = lcnt[lane];
        int v = c;
#pragma unroll
        for (int off = 1; off < 64; off <<= 1) {
            int t = __shfl_up(v, off, 64);
            if (lane >= off) v += t;
        }
        loff[lane] = v - c;
        lcur[lane] = v - c;
        if (lane == 63) loff[64] = v;  // == m
    }
    __syncthreads();
    for (int i = tid; i < m; i += 256) {
        unsigned pk = eraw[i];
        int pos = atomicAdd(&lcur[pk >> 17], 1);
        eled[pos] = pk & 0x1FFFFu;
    }
    __syncthreads();

    int nbase = b * 64;
#pragma unroll 1
    for (int t = 0; t < 16; t++) {
        int nl = wid * 16 + t;
        int s0 = loff[nl], s1 = loff[nl + 1];
        float acc = 0.f;
        for (int k = s0; k < s1; k += 16) {
            int cnt = s1 - k; if (cnt > 16) cnt = 16;   // wave-uniform
            unsigned sv = eled[min(k + (lane & 15), s1 - 1)];
            float v[16];
#pragma unroll
            for (int j = 0; j < 16; j++) {
                if (j < cnt) {
                    int sj = __shfl((int)sv, j, 64);
                    v[j] = xs[(size_t)sj * 64 + lane];
                }
            }
#pragma unroll
            for (int j = 0; j < 16; j++)
                if (j < cnt) acc += v[j];
        }
        int g = nbase + nl;
        if (g < N_NODESC) {
            float isq = rsqrtf(fmaxf((float)(s1 - s0), 1.f));
            h2[(size_t)g * 64 + lane] = acc * isq;
        }
    }
}

// ---------------- channel-attention scores (sum over nodes) ----------------
__global__ __launch_bounds__(256) void att_kernel(const float* __restrict__ h1,
                                                  const float* __restrict__ h2,
                                                  const float* __restrict__ aw1,
                                                  const float* __restrict__ ab1,
                                                  const float* __restrict__ aw2,
                                                  float* __restrict__ wsum) {
    int n = blockIdx.x * 256 + threadIdx.x;
    float sc[2] = {0.f, 0.f};
    if (n < N_NODESC) {
#pragma unroll
        for (int c = 0; c < 2; c++) {
            const float* row = (c == 0 ? h1 : h2) + (size_t)n * 64;
            float acc[32];
#pragma unroll
            for (int k = 0; k < 32; k++) acc[k] = ab1[k];
            for (int fq = 0; fq < 16; fq++) {
                float4 rv = ((const float4*)row)[fq];
#pragma unroll
                for (int k = 0; k < 32; k++) {
                    acc[k] += rv.x * aw1[(fq * 4 + 0) * 32 + k]
                            + rv.y * aw1[(fq * 4 + 1) * 32 + k]
                            + rv.z * aw1[(fq * 4 + 2) * 32 + k]
                            + rv.w * aw1[(fq * 4 + 3) * 32 + k];
                }
            }
            float s = 0.f;
#pragma unroll
            for (int k = 0; k < 32; k++) s += tanhf(acc[k]) * aw2[k];
            sc[c] = s;
        }
    }
#pragma unroll
    for (int off = 32; off; off >>= 1) {
        sc[0] += __shfl_down(sc[0], off, 64);
        sc[1] += __shfl_down(sc[1], off, 64);
    }
    if ((threadIdx.x & 63) == 0) {
        atomicAdd(&wsum[0], sc[0]);
        atomicAdd(&wsum[1], sc[1]);
    }
}

__global__ void beta_kernel(const float* __restrict__ wsum, float* __restrict__ beta) {
    float w0 = wsum[0] / (float)N_NODESC, w1 = wsum[1] / (float)N_NODESC;
    float m = fmaxf(w0, w1);
    float e0 = expf(w0 - m), e1 = expf(w1 - m);
    float inv = 1.f / (e0 + e1);
    beta[0] = e0 * inv;
    beta[1] = e1 * inv;
}

// ---------------- fused combine + fc2 ----------------
__global__ __launch_bounds__(256) void out_kernel(const float* __restrict__ h1,
                                                  const float* __restrict__ h2,
                                                  const float* __restrict__ beta,
                                                  const float* __restrict__ w,
                                                  const float* __restrict__ b,
                                                  float* __restrict__ out) {
    __shared__ float sw[16 * 68];
    int tid = threadIdx.x;
    {
        int o = tid >> 4, f4 = tid & 15;
        float4 v = ((const float4*)w)[tid];
        float* d = &sw[o * 68 + f4 * 4];
        d[0] = v.x; d[1] = v.y; d[2] = v.z; d[3] = v.w;
    }
    __syncthreads();
    int o = tid & 15, ln = tid >> 4;
    int node = blockIdx.x * 16 + ln;
    if (node >= N_NODESC) return;
    float b0 = beta[0], b1v = beta[1];
    const float4* r1 = (const float4*)(h1 + (size_t)node * 64);
    const float4* r2 = (const float4*)(h2 + (size_t)node * 64);
    float acc = b[o];
    for (int fq = 0; fq < 16; fq++) {
        float4 x1 = r1[fq], x2 = r2[fq];
        float4 wv = *(const float4*)&sw[o * 68 + fq * 4];
        acc += (b0 * x1.x + b1v * x2.x) * wv.x + (b0 * x1.y + b1v * x2.y) * wv.y
             + (b0 * x1.z + b1v * x2.z) * wv.z + (b0 * x1.w + b1v * x2.w) * wv.w;
    }
    out[(size_t)node * 16 + o] = acc;
}

extern "C" void kernel_launch(void* const* d_in, const int* in_sizes, int n_in,
                              void* d_out, int out_size, void* d_ws, size_t ws_size,
                              hipStream_t stream) {
    (void)in_sizes; (void)n_in; (void)out_size; (void)ws_size;
    const float* feat = (const float*)d_in[0];
    const int*   esrc = (const int*)d_in[1];
    const int*   edst = (const int*)d_in[2];
    const float* fc1w = (const float*)d_in[3];
    const float* fc1b = (const float*)d_in[4];
    const float* fltw = (const float*)d_in[5];
    const float* fltb = (const float*)d_in[6];
    const float* aw1  = (const float*)d_in[7];
    const float* ab1  = (const float*)d_in[8];
    const float* aw2  = (const float*)d_in[9];
    const float* fc2w = (const float*)d_in[10];
    const float* fc2b = (const float*)d_in[11];
    float* out = (float*)d_out;

    char* ws = (char*)d_ws;
    size_t off = 0;
    auto alloc = [&](size_t bytes) {
        char* p = ws + off;
        off += (bytes + 255) & ~(size_t)255;
        return p;
    };
    float*    h1      = (float*)alloc((size_t)N_NODESC * 64 * 4);
    float*    xs      = (float*)alloc((size_t)N_NODESC * 64 * 4);
    float*    h2      = (float*)alloc((size_t)N_NODESC * 64 * 4);
    int*      deg_out = (int*)alloc((size_t)N_NODESC * 4);
    int*      bcur    = (int*)alloc((size_t)NBUCK * 4);
    unsigned* bedges  = (unsigned*)alloc((size_t)NBUCK * BSLACK * 4);  // 8 MB
    float*    wsum    = (float*)alloc(16 * 4);
    float*    beta    = (float*)alloc(16 * 4);

    hipMemsetAsync(deg_out, 0, (size_t)N_NODESC * 4, stream);
    hipMemsetAsync(wsum, 0, 2 * 4, stream);

    binit_kernel<<<(NBUCK + 255) / 256, 256, 0, stream>>>(bcur);
    deg_kernel<<<(N_EDGESC + 255) / 256, 256, 0, stream>>>(esrc, deg_out);
    scatter2_kernel<<<NSBLK, 1024, 0, stream>>>(esrc, edst, bcur, bedges);
    gemm_kernel<<<(N_NODESC + 127) / 128, 256, 0, stream>>>(
        feat, fc1w, fc1b, fltw, fltb, deg_out, h1, xs);
    agg4_kernel<<<NBUCK, 256, 0, stream>>>(bcur, bedges, xs, h2);
    att_kernel<<<(N_NODESC + 255) / 256, 256, 0, stream>>>(h1, h2, aw1, ab1, aw2, wsum);
    beta_kernel<<<1, 1, 0, stream>>>(wsum, beta);
    out_kernel<<<(N_NODESC + 15) / 16, 256, 0, stream>>>(h1, h2, beta, fc2w, fc2b, out);
}